// Round 4
// baseline (242.013 us; speedup 1.0000x reference)
//
#include <hip/hip_runtime.h>
#include <hip/hip_bf16.h>
#include <hip/hip_cooperative_groups.h>

namespace cg = cooperative_groups;

// Shapes hardcoded: b=16, S=512, IN=256, OUT=128, NB=6, Lo=256, actual_seq_len=512
#define LN_EPS 1e-5f

// Fragment-native layouts (consumer MFMA short8 loads coalesced):
//   W3  [s][ig(8)][kq(16)][il(16)][8] : k2b B wave-load = 1KB contiguous
//   Z2  [s][kq][b][8]                 : k2b A wave-load = 1KB contiguous
//   Lc2 [kq][o][8]                    : k3 A-frags = 4x256B segments
//   TR2 [b][kq][i][8]                 : k3 B-frags = 4x256B segments

typedef __attribute__((ext_vector_type(8))) short short8;   // 8 bf16 = 4 VGPR (MFMA A/B frag)
typedef __attribute__((ext_vector_type(4))) float floatx4;  // MFMA C/D frag

__device__ __forceinline__ unsigned short f2bf(float f) {
    __hip_bfloat16 h = __float2bfloat16(f);
    union { __hip_bfloat16 h; unsigned short u; } v; v.h = h; return v.u;
}
__device__ __forceinline__ unsigned int pack2(float a, float b) {
    return (unsigned int)f2bf(a) | ((unsigned int)f2bf(b) << 16);
}

union SMem {
    struct { float buf[32 * 258]; float red1[256]; float red2[256]; float mus[32]; float rsg[32]; } p1;
    struct { unsigned short axs[32 * 40]; unsigned short bs[256 * 40]; } stg;   // aliases p1.buf (K-loop only)
    unsigned short lcat[32 * 260];
    unsigned short tbuf[16 * 64 * 4];     // k2b phase
    float red[4 * 32 * 64];               // k3 phase
};

// ---- role: W3 recurrence (one vb in 0..511) ----
__device__ void role_w(int vb, int t, const float* __restrict__ P,
                       const float* __restrict__ periods, unsigned short* __restrict__ W) {
    int et = vb & 31, sc = vb >> 5;
    int n0 = et * 512 + t * 2;
    // W3 flat: n = ((ig*16 + kq)*16 + il)*8 + jj ;  i = ig*16+il, j = kq*8+jj
    int jj = n0 & 7, il = (n0 >> 3) & 15, kq = (n0 >> 7) & 15, ig = (n0 >> 11) & 7;
    int e0 = (ig * 16 + il) * 128 + kq * 8 + jj;   // i*128 + j
    const float* pp = P + (size_t)e0 * 6;
    float4 pa = *(const float4*)(pp);
    float4 pb = *(const float4*)(pp + 4);
    float4 pc = *(const float4*)(pp + 8);
    float pf[12] = { pa.x, pa.y, pa.z, pa.w, pb.x, pb.y, pb.z, pb.w, pc.x, pc.y, pc.z, pc.w };
    const float* qp = periods + (size_t)e0 * 6;
    float4 qa = *(const float4*)(qp);
    float4 qb = *(const float4*)(qp + 4);
    float4 qc = *(const float4*)(qp + 8);
    float iv[12] = { __builtin_amdgcn_rcpf(qa.x), __builtin_amdgcn_rcpf(qa.y),
                     __builtin_amdgcn_rcpf(qa.z), __builtin_amdgcn_rcpf(qa.w),
                     __builtin_amdgcn_rcpf(qb.x), __builtin_amdgcn_rcpf(qb.y),
                     __builtin_amdgcn_rcpf(qb.z), __builtin_amdgcn_rcpf(qb.w),
                     __builtin_amdgcn_rcpf(qc.x), __builtin_amdgcn_rcpf(qc.y),
                     __builtin_amdgcn_rcpf(qc.z), __builtin_amdgcn_rcpf(qc.w) };
    float s0f = (float)(sc * 32);
    float tc[12], cm1[12], cc[12];
    #pragma unroll
    for (int g = 0; g < 12; ++g) {
        tc[g]  = 2.0f * __builtin_amdgcn_cosf(iv[g]);  // 1/p <= 0.5, already in [0,1)
        cm1[g] = __builtin_amdgcn_cosf(__builtin_amdgcn_fractf(s0f * iv[g]));
        cc[g]  = __builtin_amdgcn_cosf(__builtin_amdgcn_fractf((s0f + 1.0f) * iv[g]));
    }
    #pragma unroll 4
    for (int ss = 0; ss < 32; ++ss) {
        float a0 = 0.f, a1 = 0.f;
        #pragma unroll
        for (int g = 0; g < 6; ++g)  a0 += pf[g] * cm1[g];
        #pragma unroll
        for (int g = 6; g < 12; ++g) a1 += pf[g] * cm1[g];
        int s = sc * 32 + ss;
        *(unsigned int*)(W + (size_t)s * 16384 + n0) = pack2(a0, a1);
        #pragma unroll
        for (int g = 0; g < 12; ++g) {
            float cn = fmaf(tc[g], cc[g], -cm1[g]);
            cm1[g] = cc[g]; cc[g] = cn;
        }
    }
}

// ---- role: k1 ZR = x @ [M;resW]^T + LN (one vb in 0..255) ----
__device__ void role_k1(SMem& sm, int vb, int t,
                        const float* __restrict__ x, const float* __restrict__ M,
                        const float* __restrict__ resW, const float* __restrict__ gamma,
                        const float* __restrict__ beta,
                        unsigned short* __restrict__ Z, unsigned short* __restrict__ TRt) {
    int w = t >> 6, l = t & 63;
    int lane15 = l & 15, quad = l >> 4;
    int r0 = vb * 32;
    int wco = w * 64;                        // wave's output-col base (0..192)
    floatx4 acc[2][4] = {};
    for (int km = 0; km < 256; km += 32) {
        // stage A: x[r0..r0+31][km..km+31] f32 -> bf16 axs[32][40]
        {
            int row = t >> 3, c4 = (t & 7) * 4;
            float4 v = *(const float4*)(x + (size_t)(r0 + row) * 256 + km + c4);
            uint2 u; u.x = pack2(v.x, v.y); u.y = pack2(v.z, v.w);
            *(uint2*)(sm.stg.axs + row * 40 + c4) = u;
        }
        // stage B: [M;resW][0..255][km..km+31] f32 -> bf16 bs[256][40]
        #pragma unroll
        for (int q = 0; q < 8; ++q) {
            int idx = t + 256 * q;
            int row = idx >> 3, c4 = (idx & 7) * 4;
            const float* src = (row < 128) ? (M + (size_t)row * 256)
                                           : (resW + (size_t)(row - 128) * 256);
            float4 v = *(const float4*)(src + km + c4);
            uint2 u; u.x = pack2(v.x, v.y); u.y = pack2(v.z, v.w);
            *(uint2*)(sm.stg.bs + row * 40 + c4) = u;
        }
        __syncthreads();
        int k0 = quad * 8;
        short8 a0 = *(const short8*)(sm.stg.axs + lane15 * 40 + k0);
        short8 a1 = *(const short8*)(sm.stg.axs + (16 + lane15) * 40 + k0);
        #pragma unroll
        for (int nt = 0; nt < 4; ++nt) {
            short8 b = *(const short8*)(sm.stg.bs + (wco + nt * 16 + lane15) * 40 + k0);
            acc[0][nt] = __builtin_amdgcn_mfma_f32_16x16x32_bf16(a0, b, acc[0][nt], 0, 0, 0);
            acc[1][nt] = __builtin_amdgcn_mfma_f32_16x16x32_bf16(a1, b, acc[1][nt], 0, 0, 0);
        }
        __syncthreads();                     // also protects stg before buf alias-write
    }
    #pragma unroll
    for (int mt = 0; mt < 2; ++mt)
        #pragma unroll
        for (int nt = 0; nt < 4; ++nt)
            #pragma unroll
            for (int r = 0; r < 4; ++r) {
                int ro = mt * 16 + quad * 4 + r;
                int co = w * 64 + nt * 16 + lane15;
                sm.p1.buf[ro * 258 + co] = acc[mt][nt][r];
            }
    __syncthreads();
    {
        int r = t >> 3, seg = t & 7;
        float s1 = 0.f, s2 = 0.f;
        #pragma unroll
        for (int e = 0; e < 16; ++e) { float v = sm.p1.buf[r * 258 + seg * 16 + e]; s1 += v; s2 += v * v; }
        sm.p1.red1[r * 8 + seg] = s1; sm.p1.red2[r * 8 + seg] = s2;
    }
    __syncthreads();
    if (t < 32) {
        float s1 = 0.f, s2 = 0.f;
        #pragma unroll
        for (int e = 0; e < 8; ++e) { s1 += sm.p1.red1[t * 8 + e]; s2 += sm.p1.red2[t * 8 + e]; }
        float mu = s1 * (1.0f / 128.0f);
        float var = s2 * (1.0f / 128.0f) - mu * mu;
        sm.p1.mus[t] = mu; sm.p1.rsg[t] = rsqrtf(var + LN_EPS);
    }
    __syncthreads();
    int b = r0 >> 9, s0 = r0 & 511;
    {   // Z writeout -> Z2[s][kq][b][8]
        int r = t >> 3, c0 = (t & 7) * 16;
        int s_t = s0 + r;
        float mu = sm.p1.mus[r], rs = sm.p1.rsg[r];
        float zv[16];
        #pragma unroll
        for (int e = 0; e < 16; ++e) {
            int j = c0 + e;
            zv[e] = (sm.p1.buf[r * 258 + j] - mu) * rs * gamma[j] + beta[j];
        }
        uint4 oz0, oz1;
        oz0.x = pack2(zv[0], zv[1]);  oz0.y = pack2(zv[2], zv[3]);
        oz0.z = pack2(zv[4], zv[5]);  oz0.w = pack2(zv[6], zv[7]);
        oz1.x = pack2(zv[8], zv[9]);  oz1.y = pack2(zv[10], zv[11]);
        oz1.z = pack2(zv[12], zv[13]); oz1.w = pack2(zv[14], zv[15]);
        unsigned short* zdst = Z + (size_t)s_t * 2048 + (((c0 >> 3) * 16 + b) << 3);
        *(uint4*)(zdst) = oz0;
        *(uint4*)(zdst + 128) = oz1;        // next kq group: +16*8 elements
    }
    {   // R writeout -> TR2[b][kq][j][8], k = 512+s
        int j = t >> 1, sh = (t & 1) * 16;
        unsigned int ow[8];
        #pragma unroll
        for (int p = 0; p < 8; ++p) {
            float v0 = sm.p1.buf[(sh + 2 * p) * 258 + 128 + j];
            float v1 = sm.p1.buf[(sh + 2 * p + 1) * 258 + 128 + j];
            ow[p] = pack2(v0, v1);
        }
        int kqA = 64 + ((s0 + sh) >> 3);     // k = 512+s0+sh
        unsigned short* dst = TRt + (size_t)b * 131072 + ((size_t)(kqA * 128 + j) << 3);
        uint4 u0; u0.x = ow[0]; u0.y = ow[1]; u0.z = ow[2]; u0.w = ow[3];
        uint4 u1; u1.x = ow[4]; u1.y = ow[5]; u1.z = ow[6]; u1.w = ow[7];
        *(uint4*)(dst) = u0;
        *(uint4*)(dst + 1024) = u1;          // next kq group: +128*8 elements
    }
}

// ---- role: Lc2 transpose (one vb in 0..31) ----
__device__ void role_lc(SMem& sm, int vb, int t, const float* __restrict__ Linker,
                        const float* __restrict__ resL, unsigned short* __restrict__ LcatT) {
    int kb = vb;                        // 0..31
    int k0 = kb * 32;
    const float* src = (kb < 16) ? (Linker + (size_t)k0 * 256)
                                 : (resL + (size_t)(k0 - 512) * 256);
    #pragma unroll
    for (int q = 0; q < 8; ++q) {
        int lin = t + 256 * q;
        int row = lin >> 6, col4 = (lin & 63) * 4;
        float4 v = *(const float4*)(src + row * 256 + col4);
        *(unsigned int*)(sm.lcat + row * 260 + col4)     = pack2(v.x, v.y);
        *(unsigned int*)(sm.lcat + row * 260 + col4 + 2) = pack2(v.z, v.w);
    }
    __syncthreads();
    int o = t;
    unsigned int outw[16];
    #pragma unroll
    for (int kp = 0; kp < 16; ++kp) {
        unsigned int lo = sm.lcat[(2 * kp) * 260 + o];
        unsigned int hi = sm.lcat[(2 * kp + 1) * 260 + o];
        outw[kp] = lo | (hi << 16);
    }
    #pragma unroll
    for (int qq = 0; qq < 4; ++qq) {
        uint4 u; u.x = outw[qq*4]; u.y = outw[qq*4+1]; u.z = outw[qq*4+2]; u.w = outw[qq*4+3];
        *(uint4*)(LcatT + (((size_t)(kb * 4 + qq) * 256 + o) << 3)) = u;
    }
    __syncthreads();                    // LDS quiesced before any later phase reuse
}

// ---- role: k2b T -> TR2 (one vb in 0..255) ----
__device__ void role_k2b(SMem& sm, int vb, int t, const unsigned short* __restrict__ W,
                         const unsigned short* __restrict__ Z, unsigned short* __restrict__ TRt) {
    int w = t >> 6, l = t & 63;
    int lane15 = l & 15, quad = l >> 4;
    int st = vb >> 1, ih = vb & 1;
    int s0 = st * 4;
    int ig = ih * 4 + w;                           // wave's 16-i group (W3 ig index)
    #pragma unroll
    for (int ss = 0; ss < 4; ++ss) {
        int s = s0 + ss;
        floatx4 acc = {};
        #pragma unroll
        for (int kk = 0; kk < 4; ++kk) {
            int kq = kk * 4 + quad;
            short8 a  = *(const short8*)(Z + (size_t)s * 2048 + ((kq * 16 + lane15) << 3));
            short8 bf = *(const short8*)(W + (size_t)s * 16384 + (((ig * 16 + kq) * 16 + lane15) << 3));
            acc = __builtin_amdgcn_mfma_f32_16x16x32_bf16(a, bf, acc, 0, 0, 0);
        }
        int il = w * 16 + lane15;
        #pragma unroll
        for (int r = 0; r < 4; ++r) {
            int brow = quad * 4 + r;               // batch index (D row)
            sm.tbuf[(brow * 64 + il) * 4 + ss] = f2bf(acc[r]);
        }
    }
    __syncthreads();
    // writeout: 1024 (b,il) pairs, 8B (4 s within kq=s0>>3) each
    int ihb = ih * 64;
    #pragma unroll
    for (int q = 0; q < 4; ++q) {
        int p = t + 256 * q;
        int b = p >> 6, il = p & 63;
        uint2 v = *(const uint2*)(sm.tbuf + p * 4);
        *(uint2*)(TRt + (size_t)b * 131072 + (((s0 >> 3) * 128 + ihb + il) << 3) + (s0 & 7)) = v;
    }
}

// ---- role: k3 out (one vb in 0..255) ----
__device__ void role_k3(SMem& sm, int vb, int t, const unsigned short* __restrict__ LcatT,
                        const unsigned short* __restrict__ TRt, float* __restrict__ out) {
    int w = t >> 6, l = t & 63;
    int lane15 = l & 15, quad = l >> 4;
    int b = vb & 15, o0 = ((vb >> 4) & 7) * 32, i0 = (vb >> 7) * 64;
    const unsigned short* trb = TRt + (size_t)b * 131072;
    floatx4 acc[2][4] = {};
    #pragma unroll 2
    for (int kk = 0; kk < 8; ++kk) {
        int k0 = w * 256 + kk * 32 + quad * 8;
        int kq = k0 >> 3;
        short8 afr0 = *(const short8*)(LcatT + (((size_t)kq * 256 + o0 + lane15) << 3));
        short8 afr1 = *(const short8*)(LcatT + (((size_t)kq * 256 + o0 + 16 + lane15) << 3));
        #pragma unroll
        for (int nt = 0; nt < 4; ++nt) {
            short8 bfr = *(const short8*)(trb + (((size_t)kq * 128 + i0 + nt * 16 + lane15) << 3));
            acc[0][nt] = __builtin_amdgcn_mfma_f32_16x16x32_bf16(afr0, bfr, acc[0][nt], 0, 0, 0);
            acc[1][nt] = __builtin_amdgcn_mfma_f32_16x16x32_bf16(afr1, bfr, acc[1][nt], 0, 0, 0);
        }
    }
    #pragma unroll
    for (int mt = 0; mt < 2; ++mt)
        #pragma unroll
        for (int nt = 0; nt < 4; ++nt)
            #pragma unroll
            for (int r = 0; r < 4; ++r) {
                int ro = mt * 16 + quad * 4 + r;
                int co = nt * 16 + lane15;
                sm.red[(w * 32 + ro) * 64 + co] = acc[mt][nt][r];
            }
    __syncthreads();
    {
        int ro = t >> 3, c0 = (t & 7) * 8;
        float vs[8];
        #pragma unroll
        for (int e = 0; e < 8; ++e) {
            float sum = 0.f;
            #pragma unroll
            for (int ww = 0; ww < 4; ++ww) sum += sm.red[(ww * 32 + ro) * 64 + c0 + e];
            vs[e] = sum;
        }
        float4 o1 = { vs[0], vs[1], vs[2], vs[3] };
        float4 o2 = { vs[4], vs[5], vs[6], vs[7] };
        size_t ob = ((size_t)b * 256 + o0 + ro) * 128 + i0 + c0;
        *(float4*)(out + ob) = o1;
        *(float4*)(out + ob + 4) = o2;
    }
}

// ---------------- mega: single cooperative launch, 512 blocks x 256 threads ----------------
// phase1: blk<256 -> k1(blk); blk>=256 -> 2x W items (+Lc for blk 256..287)
// phase2: blk<256 -> k2b(blk)
// phase3: blk<256 -> k3(blk)
__global__ __launch_bounds__(256, 2) void mega(const float* __restrict__ x,
                                               const float* __restrict__ M,
                                               const float* __restrict__ resW,
                                               const float* __restrict__ gamma,
                                               const float* __restrict__ beta,
                                               const float* __restrict__ P,
                                               const float* __restrict__ periods,
                                               const float* __restrict__ Linker,
                                               const float* __restrict__ resL,
                                               unsigned short* __restrict__ Z,
                                               unsigned short* __restrict__ TRt,
                                               unsigned short* __restrict__ W,
                                               unsigned short* __restrict__ LcatT,
                                               float* __restrict__ out) {
    __shared__ SMem sm;
    cg::grid_group grid = cg::this_grid();
    int blk = blockIdx.x, t = threadIdx.x;

    // ---- phase 1: producers ----
    if (blk < 256) {
        role_k1(sm, blk, t, x, M, resW, gamma, beta, Z, TRt);
    } else {
        if (blk < 288) role_lc(sm, blk - 256, t, Linker, resL, LcatT);
        int v0 = (blk - 256) * 2;
        role_w(v0, t, P, periods, W);
        role_w(v0 + 1, t, P, periods, W);
    }
    grid.sync();

    // ---- phase 2: T GEMM ----
    if (blk < 256) role_k2b(sm, blk, t, W, Z, TRt);
    grid.sync();

    // ---- phase 3: output GEMM ----
    if (blk < 256) role_k3(sm, blk, t, LcatT, TRt, out);
}

extern "C" void kernel_launch(void* const* d_in, const int* in_sizes, int n_in,
                              void* d_out, int out_size, void* d_ws, size_t ws_size,
                              hipStream_t stream) {
    const float* x      = (const float*)d_in[0];
    const float* M      = (const float*)d_in[1];
    const float* P      = (const float*)d_in[2];
    const float* Linker = (const float*)d_in[3];
    const float* gamma  = (const float*)d_in[4];
    const float* beta   = (const float*)d_in[5];
    const float* resW   = (const float*)d_in[6];
    const float* resL   = (const float*)d_in[7];
    const float* periods= (const float*)d_in[8];
    (void)in_sizes; (void)n_in; (void)out_size; (void)ws_size;

    float* ws = (float*)d_ws;
    // ws layout (float offsets):
    //   Lc2 [0,       131072)    [kq][o][8]              256x1024 bf16
    //   Z2  [131072,  655360)    [s][kq][b][8]           512x2048 bf16
    //   TR2 [655360,  1703936)   [b][kq][i][8]           16x1024x128 bf16 (kq<64: T, kq>=64: R)
    //   W3  [1703936, 5898240)   [s][ig][kq][il][8]      512x16384 bf16
    unsigned short* LcatT = (unsigned short*)(ws);
    unsigned short* Z     = (unsigned short*)(ws + 131072);
    unsigned short* TRt   = (unsigned short*)(ws + 655360);
    unsigned short* W     = (unsigned short*)(ws + 1703936);
    float* outp = (float*)d_out;

    void* args[] = { (void*)&x, (void*)&M, (void*)&resW, (void*)&gamma, (void*)&beta,
                     (void*)&P, (void*)&periods, (void*)&Linker, (void*)&resL,
                     (void*)&Z, (void*)&TRt, (void*)&W, (void*)&LcatT, (void*)&outp };
    hipLaunchCooperativeKernel((const void*)mega, dim3(512), dim3(256), args, 0, stream);
}

// Round 5
// 102.690 us; speedup vs baseline: 2.3567x; 2.3567x over previous
//
#include <hip/hip_runtime.h>
#include <hip/hip_bf16.h>

// Shapes hardcoded: b=16, S=512, IN=256, OUT=128, NB=6, Lo=256, actual_seq_len=512
#define LN_EPS 1e-5f

// Fragment-native layouts (consumer MFMA short8 loads coalesced):
//   W3  [s][ig(8)][kq(16)][il(16)][8] : k2b B wave-load = 1KB contiguous
//   Z2  [s][kq][b][8]                 : k2b A wave-load = 1KB contiguous
//   Lc2 [kq][o][8]                    : k3 A-frags = 4x256B segments
//   TR2 [b][kq][i][8]                 : k3 B-frags = 4x256B segments

typedef __attribute__((ext_vector_type(8))) short short8;   // 8 bf16 = 4 VGPR (MFMA A/B frag)
typedef __attribute__((ext_vector_type(4))) float floatx4;  // MFMA C/D frag

__device__ __forceinline__ unsigned short f2bf(float f) {
    __hip_bfloat16 h = __float2bfloat16(f);
    union { __hip_bfloat16 h; unsigned short u; } v; v.h = h; return v.u;
}
__device__ __forceinline__ unsigned int pack2(float a, float b) {
    return (unsigned int)f2bf(a) | ((unsigned int)f2bf(b) << 16);
}

union SMem {
    struct { float buf[32 * 258]; float red1[256]; float red2[256]; float mus[32]; float rsg[32]; } p1;
    struct { unsigned short axs[32 * 40]; unsigned short bs[256 * 40]; } stg;   // aliases p1.buf (K-loop only)
    unsigned short lcat[32 * 260];
};

// ---------------- s1: all independent producers in one launch (NO grid sync) ----------------
// blk 0..255: k1 ZR-GEMM+LN (HBM-heavy, issues x-stream first);
// blk 256..767: W3[s] via cos recurrence (VALU-heavy, overlaps with k1's memory phase);
// blk 768..799: Lc2 transpose
__global__ __launch_bounds__(256) void s1_produce(const float* __restrict__ x,
                                                  const float* __restrict__ M,
                                                  const float* __restrict__ resW,
                                                  const float* __restrict__ gamma,
                                                  const float* __restrict__ beta,
                                                  const float* __restrict__ P,
                                                  const float* __restrict__ periods,
                                                  const float* __restrict__ Linker,
                                                  const float* __restrict__ resL,
                                                  unsigned short* __restrict__ Z,
                                                  unsigned short* __restrict__ TRt,
                                                  unsigned short* __restrict__ W,
                                                  unsigned short* __restrict__ LcatT) {
    __shared__ SMem sm;
    int blk = blockIdx.x, t = threadIdx.x;
    int w = t >> 6, l = t & 63;
    int lane15 = l & 15, quad = l >> 4;

    if (blk < 256) {
        // ---- k1: ZR = x @ [M;resW]^T, LN on Z half. LDS-staged operands. ----
        int r0 = blk * 32;
        int wco = w * 64;                        // wave's output-col base (0..192)
        floatx4 acc[2][4] = {};
        for (int km = 0; km < 256; km += 32) {
            // stage A: x[r0..r0+31][km..km+31] f32 -> bf16 axs[32][40]
            {
                int row = t >> 3, c4 = (t & 7) * 4;
                float4 v = *(const float4*)(x + (size_t)(r0 + row) * 256 + km + c4);
                uint2 u; u.x = pack2(v.x, v.y); u.y = pack2(v.z, v.w);
                *(uint2*)(sm.stg.axs + row * 40 + c4) = u;
            }
            // stage B: [M;resW][0..255][km..km+31] f32 -> bf16 bs[256][40]
            #pragma unroll
            for (int q = 0; q < 8; ++q) {
                int idx = t + 256 * q;
                int row = idx >> 3, c4 = (idx & 7) * 4;
                const float* src = (row < 128) ? (M + (size_t)row * 256)
                                               : (resW + (size_t)(row - 128) * 256);
                float4 v = *(const float4*)(src + km + c4);
                uint2 u; u.x = pack2(v.x, v.y); u.y = pack2(v.z, v.w);
                *(uint2*)(sm.stg.bs + row * 40 + c4) = u;
            }
            __syncthreads();
            int k0 = quad * 8;
            short8 a0 = *(const short8*)(sm.stg.axs + lane15 * 40 + k0);
            short8 a1 = *(const short8*)(sm.stg.axs + (16 + lane15) * 40 + k0);
            #pragma unroll
            for (int nt = 0; nt < 4; ++nt) {
                short8 b = *(const short8*)(sm.stg.bs + (wco + nt * 16 + lane15) * 40 + k0);
                acc[0][nt] = __builtin_amdgcn_mfma_f32_16x16x32_bf16(a0, b, acc[0][nt], 0, 0, 0);
                acc[1][nt] = __builtin_amdgcn_mfma_f32_16x16x32_bf16(a1, b, acc[1][nt], 0, 0, 0);
            }
            __syncthreads();                     // also protects stg before buf alias-write
        }
        #pragma unroll
        for (int mt = 0; mt < 2; ++mt)
            #pragma unroll
            for (int nt = 0; nt < 4; ++nt)
                #pragma unroll
                for (int r = 0; r < 4; ++r) {
                    int ro = mt * 16 + quad * 4 + r;
                    int co = w * 64 + nt * 16 + lane15;
                    sm.p1.buf[ro * 258 + co] = acc[mt][nt][r];
                }
        __syncthreads();
        {
            int r = t >> 3, seg = t & 7;
            float s1 = 0.f, s2 = 0.f;
            #pragma unroll
            for (int e = 0; e < 16; ++e) { float v = sm.p1.buf[r * 258 + seg * 16 + e]; s1 += v; s2 += v * v; }
            sm.p1.red1[r * 8 + seg] = s1; sm.p1.red2[r * 8 + seg] = s2;
        }
        __syncthreads();
        if (t < 32) {
            float s1 = 0.f, s2 = 0.f;
            #pragma unroll
            for (int e = 0; e < 8; ++e) { s1 += sm.p1.red1[t * 8 + e]; s2 += sm.p1.red2[t * 8 + e]; }
            float mu = s1 * (1.0f / 128.0f);
            float var = s2 * (1.0f / 128.0f) - mu * mu;
            sm.p1.mus[t] = mu; sm.p1.rsg[t] = rsqrtf(var + LN_EPS);
        }
        __syncthreads();
        int b = r0 >> 9, s0 = r0 & 511;
        {   // Z writeout -> Z2[s][kq][b][8]
            int r = t >> 3, c0 = (t & 7) * 16;
            int s_t = s0 + r;
            float mu = sm.p1.mus[r], rs = sm.p1.rsg[r];
            float zv[16];
            #pragma unroll
            for (int e = 0; e < 16; ++e) {
                int j = c0 + e;
                zv[e] = (sm.p1.buf[r * 258 + j] - mu) * rs * gamma[j] + beta[j];
            }
            uint4 oz0, oz1;
            oz0.x = pack2(zv[0], zv[1]);  oz0.y = pack2(zv[2], zv[3]);
            oz0.z = pack2(zv[4], zv[5]);  oz0.w = pack2(zv[6], zv[7]);
            oz1.x = pack2(zv[8], zv[9]);  oz1.y = pack2(zv[10], zv[11]);
            oz1.z = pack2(zv[12], zv[13]); oz1.w = pack2(zv[14], zv[15]);
            unsigned short* zdst = Z + (size_t)s_t * 2048 + (((c0 >> 3) * 16 + b) << 3);
            *(uint4*)(zdst) = oz0;
            *(uint4*)(zdst + 128) = oz1;        // next kq group: +16*8 elements
        }
        {   // R writeout -> TR2[b][kq][j][8], k = 512+s
            int j = t >> 1, sh = (t & 1) * 16;
            unsigned int ow[8];
            #pragma unroll
            for (int p = 0; p < 8; ++p) {
                float v0 = sm.p1.buf[(sh + 2 * p) * 258 + 128 + j];
                float v1 = sm.p1.buf[(sh + 2 * p + 1) * 258 + 128 + j];
                ow[p] = pack2(v0, v1);
            }
            int kqA = 64 + ((s0 + sh) >> 3);     // k = 512+s0+sh
            unsigned short* dst = TRt + (size_t)b * 131072 + ((size_t)(kqA * 128 + j) << 3);
            uint4 u0; u0.x = ow[0]; u0.y = ow[1]; u0.z = ow[2]; u0.w = ow[3];
            uint4 u1; u1.x = ow[4]; u1.y = ow[5]; u1.z = ow[6]; u1.w = ow[7];
            *(uint4*)(dst) = u0;
            *(uint4*)(dst + 1024) = u1;          // next kq group: +128*8 elements
        }
    } else if (blk < 768) {
        // ---- W recurrence ----
        int vb = blk - 256;
        int et = vb & 31, sc = vb >> 5;
        int n0 = et * 512 + t * 2;
        // W3 flat: n = ((ig*16 + kq)*16 + il)*8 + jj ;  i = ig*16+il, j = kq*8+jj
        int jj = n0 & 7, il = (n0 >> 3) & 15, kq = (n0 >> 7) & 15, ig = (n0 >> 11) & 7;
        int e0 = (ig * 16 + il) * 128 + kq * 8 + jj;   // i*128 + j
        const float* pp = P + (size_t)e0 * 6;
        float4 pa = *(const float4*)(pp);
        float4 pb = *(const float4*)(pp + 4);
        float4 pc = *(const float4*)(pp + 8);
        float pf[12] = { pa.x, pa.y, pa.z, pa.w, pb.x, pb.y, pb.z, pb.w, pc.x, pc.y, pc.z, pc.w };
        const float* qp = periods + (size_t)e0 * 6;
        float4 qa = *(const float4*)(qp);
        float4 qb = *(const float4*)(qp + 4);
        float4 qc = *(const float4*)(qp + 8);
        float iv[12] = { __builtin_amdgcn_rcpf(qa.x), __builtin_amdgcn_rcpf(qa.y),
                         __builtin_amdgcn_rcpf(qa.z), __builtin_amdgcn_rcpf(qa.w),
                         __builtin_amdgcn_rcpf(qb.x), __builtin_amdgcn_rcpf(qb.y),
                         __builtin_amdgcn_rcpf(qb.z), __builtin_amdgcn_rcpf(qb.w),
                         __builtin_amdgcn_rcpf(qc.x), __builtin_amdgcn_rcpf(qc.y),
                         __builtin_amdgcn_rcpf(qc.z), __builtin_amdgcn_rcpf(qc.w) };
        float s0f = (float)(sc * 32);
        float tc[12], cm1[12], cc[12];
        #pragma unroll
        for (int g = 0; g < 12; ++g) {
            tc[g]  = 2.0f * __builtin_amdgcn_cosf(iv[g]);  // 1/p <= 0.5, already in [0,1)
            cm1[g] = __builtin_amdgcn_cosf(__builtin_amdgcn_fractf(s0f * iv[g]));
            cc[g]  = __builtin_amdgcn_cosf(__builtin_amdgcn_fractf((s0f + 1.0f) * iv[g]));
        }
        #pragma unroll 4
        for (int ss = 0; ss < 32; ++ss) {
            float a0 = 0.f, a1 = 0.f;
            #pragma unroll
            for (int g = 0; g < 6; ++g)  a0 += pf[g] * cm1[g];
            #pragma unroll
            for (int g = 6; g < 12; ++g) a1 += pf[g] * cm1[g];
            int s = sc * 32 + ss;
            *(unsigned int*)(W + (size_t)s * 16384 + n0) = pack2(a0, a1);
            #pragma unroll
            for (int g = 0; g < 12; ++g) {
                float cn = fmaf(tc[g], cc[g], -cm1[g]);
                cm1[g] = cc[g]; cc[g] = cn;
            }
        }
    } else {
        // ---- Lc2 transpose -> Lc2[kq][o][8] ----
        int kb = blk - 768;                 // 0..31
        int k0 = kb * 32;
        const float* src = (kb < 16) ? (Linker + (size_t)k0 * 256)
                                     : (resL + (size_t)(k0 - 512) * 256);
        #pragma unroll
        for (int q = 0; q < 8; ++q) {
            int lin = t + 256 * q;
            int row = lin >> 6, col4 = (lin & 63) * 4;
            float4 v = *(const float4*)(src + row * 256 + col4);
            *(unsigned int*)(sm.lcat + row * 260 + col4)     = pack2(v.x, v.y);
            *(unsigned int*)(sm.lcat + row * 260 + col4 + 2) = pack2(v.z, v.w);
        }
        __syncthreads();
        int o = t;
        unsigned int outw[16];
        #pragma unroll
        for (int kp = 0; kp < 16; ++kp) {
            unsigned int lo = sm.lcat[(2 * kp) * 260 + o];
            unsigned int hi = sm.lcat[(2 * kp + 1) * 260 + o];
            outw[kp] = lo | (hi << 16);
        }
        #pragma unroll
        for (int qq = 0; qq < 4; ++qq) {
            uint4 u; u.x = outw[qq*4]; u.y = outw[qq*4+1]; u.z = outw[qq*4+2]; u.w = outw[qq*4+3];
            *(uint4*)(LcatT + (((size_t)(kb * 4 + qq) * 256 + o) << 3)) = u;
        }
    }
}

// ---------------- k2b: T[b,s,i] via MFMA -> TR2[b][kq][i][8] ----------------
// grid 256 = (s-tile 0..127) x (i-half 0..1); block = 4 waves, each wave 16 i.
// A-frags from Z2 and B-frags from W3 are each 1KB-contiguous per wave-load.
// 4 live accumulators (one per ss) so the tbuf store is one packed ds_write_b64
// per r (bank-coverage-limited, conflict-free) instead of 4 scalar b16 writes (4-way).
__global__ __launch_bounds__(256) void k2b_t(const unsigned short* __restrict__ W,
                                             const unsigned short* __restrict__ Z,
                                             unsigned short* __restrict__ TRt) {
    __shared__ unsigned short tbuf[16 * 64 * 4];   // [b][il][ss] = 8KB
    int t = threadIdx.x, w = t >> 6, l = t & 63;
    int lane15 = l & 15, quad = l >> 4;
    int st = blockIdx.x >> 1, ih = blockIdx.x & 1;
    int s0 = st * 4;
    int ig = ih * 4 + w;                           // wave's 16-i group (W3 ig index)
    floatx4 acc[4] = {};
    #pragma unroll
    for (int ss = 0; ss < 4; ++ss) {
        int s = s0 + ss;
        #pragma unroll
        for (int kk = 0; kk < 4; ++kk) {
            int kq = kk * 4 + quad;
            short8 a  = *(const short8*)(Z + (size_t)s * 2048 + ((kq * 16 + lane15) << 3));
            short8 bf = *(const short8*)(W + (size_t)s * 16384 + (((ig * 16 + kq) * 16 + lane15) << 3));
            acc[ss] = __builtin_amdgcn_mfma_f32_16x16x32_bf16(a, bf, acc[ss], 0, 0, 0);
        }
    }
    int il = w * 16 + lane15;
    #pragma unroll
    for (int r = 0; r < 4; ++r) {
        int brow = quad * 4 + r;                   // batch index (D row)
        uint2 u; u.x = pack2(acc[0][r], acc[1][r]); u.y = pack2(acc[2][r], acc[3][r]);
        *(uint2*)(tbuf + (brow * 64 + il) * 4) = u;
    }
    __syncthreads();
    // writeout: 1024 (b,il) pairs, 8B (4 s within kq=s0>>3) each
    int ihb = ih * 64;
    #pragma unroll
    for (int q = 0; q < 4; ++q) {
        int p = t + 256 * q;
        int b = p >> 6, il2 = p & 63;
        uint2 v = *(const uint2*)(tbuf + p * 4);
        *(uint2*)(TRt + (size_t)b * 131072 + (((s0 >> 3) * 128 + ihb + il2) << 3) + (s0 & 7)) = v;
    }
}

// ---------------- k3: out[b][o][i], split-K over 4 waves; frags from Lc2/TR2 ----------------
// red row stride 66 (not 64): quad step = 8 banks -> uniform 2-way (free) vs 4-way at 64.
__global__ __launch_bounds__(256) void k3_out(const unsigned short* __restrict__ LcatT,
                                              const unsigned short* __restrict__ TRt,
                                              float* __restrict__ out) {
    __shared__ float red[4 * 32 * 66];
    int t = threadIdx.x, w = t >> 6, l = t & 63;
    int lane15 = l & 15, quad = l >> 4;
    int b = blockIdx.x, o0 = blockIdx.y * 32, i0 = blockIdx.z * 64;
    const unsigned short* trb = TRt + (size_t)b * 131072;
    floatx4 acc[2][4] = {};
    #pragma unroll 2
    for (int kk = 0; kk < 8; ++kk) {
        int k0 = w * 256 + kk * 32 + quad * 8;
        int kq = k0 >> 3;
        short8 afr0 = *(const short8*)(LcatT + (((size_t)kq * 256 + o0 + lane15) << 3));
        short8 afr1 = *(const short8*)(LcatT + (((size_t)kq * 256 + o0 + 16 + lane15) << 3));
        #pragma unroll
        for (int nt = 0; nt < 4; ++nt) {
            short8 bfr = *(const short8*)(trb + (((size_t)kq * 128 + i0 + nt * 16 + lane15) << 3));
            acc[0][nt] = __builtin_amdgcn_mfma_f32_16x16x32_bf16(afr0, bfr, acc[0][nt], 0, 0, 0);
            acc[1][nt] = __builtin_amdgcn_mfma_f32_16x16x32_bf16(afr1, bfr, acc[1][nt], 0, 0, 0);
        }
    }
    #pragma unroll
    for (int mt = 0; mt < 2; ++mt)
        #pragma unroll
        for (int nt = 0; nt < 4; ++nt)
            #pragma unroll
            for (int r = 0; r < 4; ++r) {
                int ro = mt * 16 + quad * 4 + r;
                int co = nt * 16 + lane15;
                red[(w * 32 + ro) * 66 + co] = acc[mt][nt][r];
            }
    __syncthreads();
    {
        int ro = t >> 3, c0 = (t & 7) * 8;
        float vs[8];
        #pragma unroll
        for (int e = 0; e < 8; ++e) {
            float sum = 0.f;
            #pragma unroll
            for (int ww = 0; ww < 4; ++ww) sum += red[(ww * 32 + ro) * 66 + c0 + e];
            vs[e] = sum;
        }
        float4 o1 = { vs[0], vs[1], vs[2], vs[3] };
        float4 o2 = { vs[4], vs[5], vs[6], vs[7] };
        size_t ob = ((size_t)b * 256 + o0 + ro) * 128 + i0 + c0;
        *(float4*)(out + ob) = o1;
        *(float4*)(out + ob + 4) = o2;
    }
}

extern "C" void kernel_launch(void* const* d_in, const int* in_sizes, int n_in,
                              void* d_out, int out_size, void* d_ws, size_t ws_size,
                              hipStream_t stream) {
    const float* x      = (const float*)d_in[0];
    const float* M      = (const float*)d_in[1];
    const float* P      = (const float*)d_in[2];
    const float* Linker = (const float*)d_in[3];
    const float* gamma  = (const float*)d_in[4];
    const float* beta   = (const float*)d_in[5];
    const float* resW   = (const float*)d_in[6];
    const float* resL   = (const float*)d_in[7];
    const float* periods= (const float*)d_in[8];
    (void)in_sizes; (void)n_in; (void)out_size; (void)ws_size;

    float* ws = (float*)d_ws;
    // ws layout (float offsets):
    //   Lc2 [0,       131072)    [kq][o][8]              256x1024 bf16
    //   Z2  [131072,  655360)    [s][kq][b][8]           512x2048 bf16
    //   TR2 [655360,  1703936)   [b][kq][i][8]           16x1024x128 bf16 (kq<64: T, kq>=64: R)
    //   W3  [1703936, 5898240)   [s][ig][kq][il][8]      512x16384 bf16
    unsigned short* LcatT = (unsigned short*)(ws);
    unsigned short* Z     = (unsigned short*)(ws + 131072);
    unsigned short* TRt   = (unsigned short*)(ws + 655360);
    unsigned short* W     = (unsigned short*)(ws + 1703936);

    s1_produce<<<800, 256, 0, stream>>>(x, M, resW, gamma, beta, P, periods,
                                        Linker, resL, Z, TRt, W, LcatT);
    k2b_t<<<256, 256, 0, stream>>>(W, Z, TRt);
    k3_out<<<dim3(16, 8, 2), 256, 0, stream>>>(LcatT, TRt, (float*)d_out);
}